// Round 9
// baseline (101.962 us; speedup 1.0000x reference)
//
#include <hip/hip_runtime.h>
#include <hip/hip_bf16.h>

#define NUM_AGES 100
#define FEAT 512
#define BATCH 4096
#define EPSF 1e-6f
#define INV_T 10.0f
#define INV_NORM (1.0f / ((float)BATCH * (float)(BATCH - 1)))

#define BM 128
#define BN 128
#define BK 64
// kept tiles: by <= bx, bx in [0,32) -> 32*33/2 = 528 = 8*66 (bijective XCD chunking)
#define NTILES 528

typedef __bf16 bf16_t;
typedef __bf16 v8bf __attribute__((ext_vector_type(8)));
typedef float v4f __attribute__((ext_vector_type(4)));

// async global->LDS, 16B per lane; LDS dest is wave-uniform base + lane*16
__device__ __forceinline__ void async16(const void* g, void* l) {
  __builtin_amdgcn_global_load_lds(
      (const __attribute__((address_space(1))) void*)g,
      (__attribute__((address_space(3))) void*)l, 16, 0, 0);
}

// ---------------- kernel 1: prep, wave-per-sample (v8, passed) -----------
// 512 blocks x 8 waves, one WAVE per sample; ages staged once per block in
// LDS (traffic 67MB -> 8MB); rank scan via LDS int4; butterfly reductions;
// lane owns 8 cols (float4 math, one 16B store each to zb/wb).
// Pre-swizzle: granule g=(c0>>3)&7 of row `rank` goes to physical
// g ^ (rank&7) in its 64-col K-slab (pair's staging lands it bank-balanced).
__global__ __launch_bounds__(512) void prep_kernel(
    const float* __restrict__ z, const int* __restrict__ ages,
    const float* __restrict__ proxies,
    bf16_t* __restrict__ zb, bf16_t* __restrict__ wb,
    float* __restrict__ sq, float* __restrict__ hd,
    int* __restrict__ ages_s, float* __restrict__ out)
{
  __shared__ __attribute__((aligned(16))) int sa[BATCH];   // 16 KB
  int t = threadIdx.x;
  int wv = t >> 6, lane = t & 63;
  if (blockIdx.x == 0 && t == 0) out[0] = 0.0f;   // pair accumulates into out

  ((int4*)sa)[t]       = ((const int4*)ages)[t];
  ((int4*)sa)[t + 512] = ((const int4*)ages)[t + 512];
  __syncthreads();

  int j = blockIdx.x * 8 + wv;          // this wave's sample
  int araw = sa[j];

  // rank scan over LDS (each lane 16 int4s, wave covers all 4096)
  int cnt = 0;
  const int4* sa4 = (const int4*)sa;
#pragma unroll
  for (int e = 0; e < 16; ++e) {
    int idx = lane + 64 * e;
    int4 v = sa4[idx];
    int k = idx * 4;
    cnt += (v.x < araw || (v.x == araw && k     < j)) ? 1 : 0;
    cnt += (v.y < araw || (v.y == araw && k + 1 < j)) ? 1 : 0;
    cnt += (v.z < araw || (v.z == araw && k + 2 < j)) ? 1 : 0;
    cnt += (v.w < araw || (v.w == araw && k + 3 < j)) ? 1 : 0;
  }

  // per-lane 8 columns
  int a  = araw < 0 ? 0 : (araw > NUM_AGES - 1 ? NUM_AGES - 1 : araw);
  int an = a + 1 > NUM_AGES - 1 ? NUM_AGES - 1 : a + 1;
  int ap = a - 1 < 0 ? 0 : a - 1;
  int c0 = lane * 8;
  const float4* cc4 = (const float4*)(proxies + (size_t)a  * FEAT + c0);
  const float4* cn4 = (const float4*)(proxies + (size_t)an * FEAT + c0);
  const float4* cp4 = (const float4*)(proxies + (size_t)ap * FEAT + c0);
  const float4* zr4 = (const float4*)(z + (size_t)j * FEAT + c0);

  float zv[8], df[8], db[8];
  float ff = 0.f, bb = 0.f, zz = 0.f, zf = 0.f, zbs = 0.f;
#pragma unroll
  for (int h = 0; h < 2; ++h) {
    float4 c4 = cc4[h], n4 = cn4[h], p4 = cp4[h], z4 = zr4[h];
    float cA[4] = {c4.x, c4.y, c4.z, c4.w};
    float nA[4] = {n4.x, n4.y, n4.z, n4.w};
    float pA[4] = {p4.x, p4.y, p4.z, p4.w};
    float zA[4] = {z4.x, z4.y, z4.z, z4.w};
#pragma unroll
    for (int i2 = 0; i2 < 4; ++i2) {
      int i = h * 4 + i2;
      zv[i] = zA[i2];
      df[i] = nA[i2] - cA[i2];
      db[i] = pA[i2] - cA[i2];
      ff  += df[i] * df[i];
      bb  += db[i] * db[i];
      zz  += zv[i] * zv[i];
      zf  += zv[i] * df[i];
      zbs += zv[i] * db[i];
    }
  }

  // 64-lane butterfly: every lane ends with the full-row sums
#pragma unroll
  for (int off = 32; off > 0; off >>= 1) {
    ff  += __shfl_xor(ff,  off, 64);
    bb  += __shfl_xor(bb,  off, 64);
    zz  += __shfl_xor(zz,  off, 64);
    zf  += __shfl_xor(zf,  off, 64);
    zbs += __shfl_xor(zbs, off, 64);
    cnt += __shfl_xor(cnt, off, 64);
  }
  int rank = cnt;
  float rf = 1.0f / (sqrtf(ff) + EPSF);
  float rb = 1.0f / (sqrtf(bb) + EPSF);
  int key = rank & 7;
  int c2s = (c0 & ~63) | ((((c0 >> 3) & 7) ^ key) << 3);  // c0&7 == 0

  union { bf16_t h[8]; uint4 u; } uz, uw;
#pragma unroll
  for (int i = 0; i < 8; ++i) {
    uz.h[i] = (bf16_t)zv[i];
    uw.h[i] = (bf16_t)(db[i] * rb - df[i] * rf);
  }
  *(uint4*)((char*)zb + ((size_t)rank * FEAT + c2s) * 2) = uz.u;
  *(uint4*)((char*)wb + ((size_t)rank * FEAT + c2s) * 2) = uw.u;
  if (lane == 0) {
    sq[rank] = zz;
    hd[rank] = rb * zbs - rf * zf;
    ages_s[rank] = araw;
  }
}

// ---------------- kernel 2: fused pairwise tile (v9: 64x64 per wave) -----
// v8 measured: pair 45.6us, MfmaUtil 13.5%, all pipes idle -> LDS-read
// serialization: 2x4 wave grid (64x32/wave) reads 128KB LDS per 48KB tile
// per K-iter (A x4, Z/W x2) = 512 B of LDS traffic per MFMA.
// v9 re-grids the SAME 128x128 tile to 4 waves (256 threads), 64x64 per
// wave (2x2 grid): afr[4]+bz[4]+bw[4] = 12 ds_read_b128 feed 64 MFMAs
// -> 192 B/MFMA, block-iter LDS reads 128KB -> 48KB (2.7x less).
// Staging bytes, swizzle, tile order, barrier scheme: byte-identical to v8
// (pure wave re-partition, m93's "bigger acc per wave" lever).
// Regs: acc 4x4x2 = 128 AGPR + ~75 VGPR ~= 200 unified <= 256 cap from
// launch_bounds(256,2) -> no spill (v4 failure mode checked), 2 waves/SIMD,
// 2 blocks/CU (LDS 51.7KB).
__global__ __launch_bounds__(256, 2) void pair_kernel(
    const bf16_t* __restrict__ zb, const bf16_t* __restrict__ wb,
    const float* __restrict__ sq, const float* __restrict__ hd,
    const int* __restrict__ ages, float* __restrict__ out)
{
  // A: 128x64 bf16 = 16384 B | Z: 128x64 = 16384 B | W: 128x64 = 16384 B
  __shared__ __attribute__((aligned(16))) char lds[49152];
  __shared__ float s_sqi[BM];
  __shared__ int   s_agei[BM];
  __shared__ float s_sqj[BN];
  __shared__ float s_hdj[BN];
  __shared__ int   s_agej[BN];
  __shared__ float wsum[4];

  int t = threadIdx.x;
  int wv = t >> 6, lane = t & 63;

  // ---- tile decode: XCD chunk + column-major triangle (by <= bx) ----
  int id = (blockIdx.x & 7) * (NTILES / 8) + (blockIdx.x >> 3);
  int bx = 0, rem = id;
  while (rem >= bx + 1) { rem -= bx + 1; ++bx; }
  int by = rem;
  int i0 = by * BM, j0 = bx * BN;

  if (t < BM) {
    s_sqi[t] = sq[i0 + t];
    s_agei[t] = ages[i0 + t];
  } else {
    int u = t - BM;   // u in [0,128)
    s_sqj[u] = sq[j0 + u];
    s_hdj[u] = hd[j0 + u];
    s_agej[u] = ages[j0 + u];
  }

  v4f accG[4][4], accH[4][4];
#pragma unroll
  for (int a = 0; a < 4; ++a)
#pragma unroll
    for (int b = 0; b < 4; ++b) {
      accG[a][b] = (v4f){0.f, 0.f, 0.f, 0.f};
      accH[a][b] = (v4f){0.f, 0.f, 0.f, 0.f};
    }

  int wm = wv >> 1, wn = wv & 1;        // wave grid 2x2: 64 rows x 64 cols each
  int lm = lane & 15, q = lane >> 4;
  // swizzled granule byte offsets for the two 32-elem slabs (key = lm&7)
  int psw0 = ((q    ) ^ (lm & 7)) * 16;
  int psw1 = ((q + 4) ^ (lm & 7)) * 16;

  // staging: per async16, lane l covers row (l>>3), physical granule (l&7)
  // of an 8-row x 128B chunk (contiguous copy preserves prep's swizzle).
  int loff = (lane >> 3) * FEAT + (lane & 7) * 8;   // bf16 elements
  const bf16_t* baseA = zb + (size_t)i0 * FEAT + loff;
  const bf16_t* baseZ = zb + (size_t)j0 * FEAT + loff;
  const bf16_t* baseW = wb + (size_t)j0 * FEAT + loff;

  for (int k0 = 0; k0 < FEAT; k0 += BK) {
    // A/Z/W: 16 chunks of 8 rows each; wave wv does chunks wv*4..wv*4+3
#pragma unroll
    for (int c = 0; c < 4; ++c) {
      int chunk = wv * 4 + c;
      async16(baseA + (size_t)chunk * 8 * FEAT + k0, lds + chunk * 1024);
      async16(baseZ + (size_t)chunk * 8 * FEAT + k0, lds + 16384 + chunk * 1024);
      async16(baseW + (size_t)chunk * 8 * FEAT + k0, lds + 32768 + chunk * 1024);
    }
    __syncthreads();   // implicit vmcnt(0): tile staged

#pragma unroll
    for (int s = 0; s < 2; ++s) {
      int psw = s ? psw1 : psw0;
      v8bf afr[4], bz[4], bw[4];
#pragma unroll
      for (int mi = 0; mi < 4; ++mi) {
        int r = wm * 64 + mi * 16 + lm;
        afr[mi] = *(const v8bf*)(lds + r * 128 + psw);
      }
#pragma unroll
      for (int ni = 0; ni < 4; ++ni) {
        int r = wn * 64 + ni * 16 + lm;
        bz[ni] = *(const v8bf*)(lds + 16384 + r * 128 + psw);
        bw[ni] = *(const v8bf*)(lds + 32768 + r * 128 + psw);
      }
#pragma unroll
      for (int mi = 0; mi < 4; ++mi)
#pragma unroll
        for (int ni = 0; ni < 4; ++ni) {
          accG[mi][ni] = __builtin_amdgcn_mfma_f32_16x16x32_bf16(afr[mi], bz[ni], accG[mi][ni], 0, 0, 0);
          accH[mi][ni] = __builtin_amdgcn_mfma_f32_16x16x32_bf16(afr[mi], bw[ni], accH[mi][ni], 0, 0, 0);
        }
    }
    __syncthreads();   // WAR: reads done before next iter's staging
  }

  // epilogue: C/D layout col = lane&15 (-> j), row = q*4 + reg (-> i)
  float tsum = 0.f;
#pragma unroll
  for (int ni = 0; ni < 4; ++ni) {
    int jl = wn * 64 + ni * 16 + lm;
    float sqj = s_sqj[jl];
    float hdj = s_hdj[jl];
    int aj = s_agej[jl];
#pragma unroll
    for (int mi = 0; mi < 4; ++mi) {
#pragma unroll
      for (int r = 0; r < 4; ++r) {
        int il = wm * 64 + mi * 16 + q * 4 + r;
        float g = accG[mi][ni][r];
        float h = accH[mi][ni][r];
        float d2 = fmaxf(s_sqi[il] + sqj - 2.0f * g, 1e-12f);
        float rs = __builtin_amdgcn_rsqf(d2);
        float arg = (h - hdj) * INV_T * rs;
        float sp = fmaxf(arg, 0.0f) + __logf(1.0f + __expf(-fabsf(arg)));
        tsum += (s_agei[il] < aj) ? sp : 0.0f;
      }
    }
  }

#pragma unroll
  for (int off = 32; off > 0; off >>= 1) tsum += __shfl_down(tsum, off, 64);
  if (lane == 0) wsum[wv] = tsum;
  __syncthreads();
  if (t == 0)
    atomicAdd(out, (wsum[0] + wsum[1] + wsum[2] + wsum[3]) * INV_NORM);
}

extern "C" void kernel_launch(void* const* d_in, const int* in_sizes, int n_in,
                              void* d_out, int out_size, void* d_ws, size_t ws_size,
                              hipStream_t stream) {
  const float* z = (const float*)d_in[0];
  const int* ages = (const int*)d_in[1];
  const float* proxies = (const float*)d_in[2];
  float* out = (float*)d_out;

  char* ws = (char*)d_ws;
  bf16_t* zb = (bf16_t*)ws;                                   // 4 MB
  bf16_t* wb = (bf16_t*)(ws + (size_t)4 * 1024 * 1024);       // 4 MB
  size_t o = (size_t)8 * 1024 * 1024;
  float* sq      = (float*)(ws + o);            // 16 KB
  float* hd      = (float*)(ws + o + 16384);    // 16 KB
  int*   ages_s  = (int*)  (ws + o + 32768);    // 16 KB

  prep_kernel<<<BATCH / 8, 512, 0, stream>>>(z, ages, proxies, zb, wb, sq, hd, ages_s, out);
  pair_kernel<<<NTILES, 256, 0, stream>>>(zb, wb, sq, hd, ages_s, out);
}

// Round 10
// 96.709 us; speedup vs baseline: 1.0543x; 1.0543x over previous
//
#include <hip/hip_runtime.h>
#include <hip/hip_bf16.h>

#define NUM_AGES 100
#define FEAT 512
#define BATCH 4096
#define EPSF 1e-6f
#define INV_T 10.0f
#define INV_NORM (1.0f / ((float)BATCH * (float)(BATCH - 1)))

#define BM 128
#define BN 128
#define BK 64
// kept tiles: by <= bx, bx in [0,32) -> 32*33/2 = 528 = 8*66 (bijective XCD chunking)
#define NTILES 528
#define UROWS 128   // U table padded to 128 rows (100 real ages + 28 zero rows)

typedef __bf16 bf16_t;
typedef __bf16 v8bf __attribute__((ext_vector_type(8)));
typedef float v4f __attribute__((ext_vector_type(4)));

// async global->LDS, 16B per lane; LDS dest is wave-uniform base + lane*16
__device__ __forceinline__ void async16(const void* g, void* l) {
  __builtin_amdgcn_global_load_lds(
      (const __attribute__((address_space(1))) void*)g,
      (__attribute__((address_space(3))) void*)l, 16, 0, 0);
}

// ---------------- kernel 1: prep (samples + U table) ---------------------
// KEY FACTORIZATION (v10): w_j = rb*(c_prev-c_cur) - rf*(c_next-c_cur)
// depends ONLY on age a_j -> 100 distinct w vectors. H[i,j] = z_i . w_{a_j}
// = ZU[i, a_j] where ZU = Z @ U^T. This deletes the W staging (68MB) and
// the H MFMA chain from the pairwise kernel (which is staging-BW bound:
// v5/v6/v8/v9 all ~43-46us across schedule variants, ~203MB/45us=4.5TB/s).
// Blocks 0..511: one wave per sample: rank scan (LDS int4) + zz butterfly +
//   bf16 z store, PRE-SWIZZLED (granule g -> g^(rank&7) per 64-col K-slab).
//   No proxy math anymore (moved to U-blocks).
// Blocks 512..527: one wave per U row a=(blk-512)*8+wv; rows >=100 zero.
//   Same pre-swizzle keyed by a&7 -> zu/pair read it like any z panel.
__global__ __launch_bounds__(512) void prep_kernel(
    const float* __restrict__ z, const int* __restrict__ ages,
    const float* __restrict__ proxies,
    bf16_t* __restrict__ zb, bf16_t* __restrict__ ub,
    float* __restrict__ sq, int* __restrict__ ages_s, float* __restrict__ out)
{
  int t = threadIdx.x;
  int wv = t >> 6, lane = t & 63;

  if (blockIdx.x >= 512) {
    // ---- U-table block: wave wv owns row a ----
    int a = (blockIdx.x - 512) * 8 + wv;   // 0..127
    int c0 = lane * 8;
    union { bf16_t h[8]; uint4 u; } uw;
    if (a < NUM_AGES) {
      int an = a + 1 > NUM_AGES - 1 ? NUM_AGES - 1 : a + 1;
      int ap = a - 1 < 0 ? 0 : a - 1;
      const float4* cc4 = (const float4*)(proxies + (size_t)a  * FEAT + c0);
      const float4* cn4 = (const float4*)(proxies + (size_t)an * FEAT + c0);
      const float4* cp4 = (const float4*)(proxies + (size_t)ap * FEAT + c0);
      float df[8], db[8];
      float ff = 0.f, bb = 0.f;
#pragma unroll
      for (int h = 0; h < 2; ++h) {
        float4 c4 = cc4[h], n4 = cn4[h], p4 = cp4[h];
        float cA[4] = {c4.x, c4.y, c4.z, c4.w};
        float nA[4] = {n4.x, n4.y, n4.z, n4.w};
        float pA[4] = {p4.x, p4.y, p4.z, p4.w};
#pragma unroll
        for (int i2 = 0; i2 < 4; ++i2) {
          int i = h * 4 + i2;
          df[i] = nA[i2] - cA[i2];
          db[i] = pA[i2] - cA[i2];
          ff += df[i] * df[i];
          bb += db[i] * db[i];
        }
      }
#pragma unroll
      for (int off = 32; off > 0; off >>= 1) {
        ff += __shfl_xor(ff, off, 64);
        bb += __shfl_xor(bb, off, 64);
      }
      float rf = 1.0f / (sqrtf(ff) + EPSF);
      float rb = 1.0f / (sqrtf(bb) + EPSF);
#pragma unroll
      for (int i = 0; i < 8; ++i)
        uw.h[i] = (bf16_t)(db[i] * rb - df[i] * rf);
    } else {
      uw.u = (uint4){0u, 0u, 0u, 0u};
    }
    int key = a & 7;
    int c2s = (c0 & ~63) | ((((c0 >> 3) & 7) ^ key) << 3);
    *(uint4*)((char*)ub + ((size_t)a * FEAT + c2s) * 2) = uw.u;
    return;
  }

  // ---- sample block: wave wv owns sample j ----
  __shared__ __attribute__((aligned(16))) int sa[BATCH];   // 16 KB
  if (blockIdx.x == 0 && t == 0) out[0] = 0.0f;   // pair accumulates into out

  ((int4*)sa)[t]       = ((const int4*)ages)[t];
  ((int4*)sa)[t + 512] = ((const int4*)ages)[t + 512];
  __syncthreads();

  int j = blockIdx.x * 8 + wv;
  int araw = sa[j];

  int cnt = 0;
  const int4* sa4 = (const int4*)sa;
#pragma unroll
  for (int e = 0; e < 16; ++e) {
    int idx = lane + 64 * e;
    int4 v = sa4[idx];
    int k = idx * 4;
    cnt += (v.x < araw || (v.x == araw && k     < j)) ? 1 : 0;
    cnt += (v.y < araw || (v.y == araw && k + 1 < j)) ? 1 : 0;
    cnt += (v.z < araw || (v.z == araw && k + 2 < j)) ? 1 : 0;
    cnt += (v.w < araw || (v.w == araw && k + 3 < j)) ? 1 : 0;
  }

  int c0 = lane * 8;
  const float4* zr4 = (const float4*)(z + (size_t)j * FEAT + c0);
  float zv[8];
  float zz = 0.f;
#pragma unroll
  for (int h = 0; h < 2; ++h) {
    float4 z4 = zr4[h];
    float zA[4] = {z4.x, z4.y, z4.z, z4.w};
#pragma unroll
    for (int i2 = 0; i2 < 4; ++i2) {
      zv[h * 4 + i2] = zA[i2];
      zz += zA[i2] * zA[i2];
    }
  }
#pragma unroll
  for (int off = 32; off > 0; off >>= 1) {
    zz  += __shfl_xor(zz,  off, 64);
    cnt += __shfl_xor(cnt, off, 64);
  }
  int rank = cnt;
  int key = rank & 7;
  int c2s = (c0 & ~63) | ((((c0 >> 3) & 7) ^ key) << 3);

  union { bf16_t h[8]; uint4 u; } uz;
#pragma unroll
  for (int i = 0; i < 8; ++i) uz.h[i] = (bf16_t)zv[i];
  *(uint4*)((char*)zb + ((size_t)rank * FEAT + c2s) * 2) = uz.u;
  if (lane == 0) {
    sq[rank] = zz;
    ages_s[rank] = araw;
  }
}

// ---------------- kernel 2: ZU = Zsorted @ U^T (32 blocks) ---------------
// Verified 4-wave 64x64 MFMA structure (v9's pair compute, minus W).
// Output ZUT[age][rank] f32 (transposed for pair's row-gathers), rows
// 100..127 are zeros (never read). float4 stores, 16B aligned.
__global__ __launch_bounds__(256, 3) void zu_kernel(
    const bf16_t* __restrict__ zb, const bf16_t* __restrict__ ub,
    float* __restrict__ zut)
{
  __shared__ __attribute__((aligned(16))) char lds[32768];
  int t = threadIdx.x;
  int wv = t >> 6, lane = t & 63;
  int r0 = blockIdx.x * 128;

  v4f acc[4][4];
#pragma unroll
  for (int a = 0; a < 4; ++a)
#pragma unroll
    for (int b = 0; b < 4; ++b) acc[a][b] = (v4f){0.f, 0.f, 0.f, 0.f};

  int wm = wv >> 1, wn = wv & 1;
  int lm = lane & 15, q = lane >> 4;
  int psw0 = ((q    ) ^ (lm & 7)) * 16;
  int psw1 = ((q + 4) ^ (lm & 7)) * 16;
  int loff = (lane >> 3) * FEAT + (lane & 7) * 8;
  const bf16_t* baseA = zb + (size_t)r0 * FEAT + loff;
  const bf16_t* baseU = ub + loff;

  for (int k0 = 0; k0 < FEAT; k0 += BK) {
#pragma unroll
    for (int c = 0; c < 4; ++c) {
      int chunk = wv * 4 + c;
      async16(baseA + (size_t)chunk * 8 * FEAT + k0, lds + chunk * 1024);
      async16(baseU + (size_t)chunk * 8 * FEAT + k0, lds + 16384 + chunk * 1024);
    }
    __syncthreads();
#pragma unroll
    for (int s = 0; s < 2; ++s) {
      int psw = s ? psw1 : psw0;
      v8bf afr[4], bu[4];
#pragma unroll
      for (int mi = 0; mi < 4; ++mi) {
        int r = wm * 64 + mi * 16 + lm;
        afr[mi] = *(const v8bf*)(lds + r * 128 + psw);
      }
#pragma unroll
      for (int ni = 0; ni < 4; ++ni) {
        int r = wn * 64 + ni * 16 + lm;
        bu[ni] = *(const v8bf*)(lds + 16384 + r * 128 + psw);
      }
#pragma unroll
      for (int mi = 0; mi < 4; ++mi)
#pragma unroll
        for (int ni = 0; ni < 4; ++ni)
          acc[mi][ni] = __builtin_amdgcn_mfma_f32_16x16x32_bf16(afr[mi], bu[ni], acc[mi][ni], 0, 0, 0);
    }
    __syncthreads();
  }

  // C/D layout: col = lane&15 -> age (B side), row = q*4+reg -> rank (A side)
#pragma unroll
  for (int ni = 0; ni < 4; ++ni) {
    int age = wn * 64 + ni * 16 + lm;
#pragma unroll
    for (int mi = 0; mi < 4; ++mi) {
      int rb0 = r0 + wm * 64 + mi * 16 + q * 4;
      *(v4f*)(zut + (size_t)age * BATCH + rb0) = acc[mi][ni];
    }
  }
}

// ---------------- kernel 3: pairwise G-GEMM + ZU-gather epilogue ---------
// v9 structure minus the entire W/H side: LDS 32KB (A+Z), 4 waves of 64x64,
// single-buffered stage->sync->compute->sync, XCD-chunked triangle order.
// Epilogue: h = ZUT[a_j][i] gathered as one float4 per (mi,ni) (rank-
// consecutive, 16B aligned); hdj = ZUT[a_j][j] staged per block.
// Staged bytes: 528 x 8 x 32KB = 135MB (was 203MB) -> if staging-BW bound
// (the v5..v9 invariance evidence), time scales ~0.67x.
// launch_bounds(256,3): 170-reg cap >= ~134 needed (64 AGPR acc + ~70),
// no spill; 3 blocks/CU (LDS 34KB) -> all 528 blocks co-resident.
__global__ __launch_bounds__(256, 3) void pair_kernel(
    const bf16_t* __restrict__ zb, const float* __restrict__ zut,
    const float* __restrict__ sq, const int* __restrict__ ages,
    float* __restrict__ out)
{
  // A: 128x64 bf16 = 16384 B | Z: 128x64 = 16384 B
  __shared__ __attribute__((aligned(16))) char lds[32768];
  __shared__ float s_sqi[BM];
  __shared__ int   s_agei[BM];
  __shared__ float s_sqj[BN];
  __shared__ float s_hdj[BN];
  __shared__ int   s_agej[BN];
  __shared__ float wsum[4];

  int t = threadIdx.x;
  int wv = t >> 6, lane = t & 63;

  // ---- tile decode: XCD chunk + column-major triangle (by <= bx) ----
  int id = (blockIdx.x & 7) * (NTILES / 8) + (blockIdx.x >> 3);
  int bx = 0, rem = id;
  while (rem >= bx + 1) { rem -= bx + 1; ++bx; }
  int by = rem;
  int i0 = by * BM, j0 = bx * BN;

  if (t < BM) {
    s_sqi[t] = sq[i0 + t];
    s_agei[t] = ages[i0 + t];
  } else {
    int u = t - BM;
    int raw = ages[j0 + u];
    int ac = raw < 0 ? 0 : (raw > NUM_AGES - 1 ? NUM_AGES - 1 : raw);
    s_sqj[u] = sq[j0 + u];
    s_agej[u] = raw;
    s_hdj[u] = zut[(size_t)ac * BATCH + j0 + u];
  }

  v4f accG[4][4];
#pragma unroll
  for (int a = 0; a < 4; ++a)
#pragma unroll
    for (int b = 0; b < 4; ++b) accG[a][b] = (v4f){0.f, 0.f, 0.f, 0.f};

  int wm = wv >> 1, wn = wv & 1;        // wave grid 2x2: 64 rows x 64 cols
  int lm = lane & 15, q = lane >> 4;
  int psw0 = ((q    ) ^ (lm & 7)) * 16;
  int psw1 = ((q + 4) ^ (lm & 7)) * 16;

  int loff = (lane >> 3) * FEAT + (lane & 7) * 8;
  const bf16_t* baseA = zb + (size_t)i0 * FEAT + loff;
  const bf16_t* baseZ = zb + (size_t)j0 * FEAT + loff;

  for (int k0 = 0; k0 < FEAT; k0 += BK) {
#pragma unroll
    for (int c = 0; c < 4; ++c) {
      int chunk = wv * 4 + c;
      async16(baseA + (size_t)chunk * 8 * FEAT + k0, lds + chunk * 1024);
      async16(baseZ + (size_t)chunk * 8 * FEAT + k0, lds + 16384 + chunk * 1024);
    }
    __syncthreads();   // implicit vmcnt(0): tile staged

#pragma unroll
    for (int s = 0; s < 2; ++s) {
      int psw = s ? psw1 : psw0;
      v8bf afr[4], bz[4];
#pragma unroll
      for (int mi = 0; mi < 4; ++mi) {
        int r = wm * 64 + mi * 16 + lm;
        afr[mi] = *(const v8bf*)(lds + r * 128 + psw);
      }
#pragma unroll
      for (int ni = 0; ni < 4; ++ni) {
        int r = wn * 64 + ni * 16 + lm;
        bz[ni] = *(const v8bf*)(lds + 16384 + r * 128 + psw);
      }
#pragma unroll
      for (int mi = 0; mi < 4; ++mi)
#pragma unroll
        for (int ni = 0; ni < 4; ++ni)
          accG[mi][ni] = __builtin_amdgcn_mfma_f32_16x16x32_bf16(afr[mi], bz[ni], accG[mi][ni], 0, 0, 0);
    }
    __syncthreads();   // WAR before next staging
  }

  // epilogue: C/D col = lane&15 (-> j), row = q*4+reg (-> i);
  // h = ZUT[a_j][i] gathered float4 (i consecutive over reg)
  float tsum = 0.f;
#pragma unroll
  for (int ni = 0; ni < 4; ++ni) {
    int jl = wn * 64 + ni * 16 + lm;
    float sqj = s_sqj[jl];
    float hdj = s_hdj[jl];
    int aj = s_agej[jl];
    int ac = aj < 0 ? 0 : (aj > NUM_AGES - 1 ? NUM_AGES - 1 : aj);
    const float* zrow = zut + (size_t)ac * BATCH + i0;
#pragma unroll
    for (int mi = 0; mi < 4; ++mi) {
      int ilb = wm * 64 + mi * 16 + q * 4;
      float4 h4 = *(const float4*)(zrow + ilb);
      float hh[4] = {h4.x, h4.y, h4.z, h4.w};
#pragma unroll
      for (int r = 0; r < 4; ++r) {
        int il = ilb + r;
        float g = accG[mi][ni][r];
        float d2 = fmaxf(s_sqi[il] + sqj - 2.0f * g, 1e-12f);
        float rs = __builtin_amdgcn_rsqf(d2);
        float arg = (hh[r] - hdj) * INV_T * rs;
        float sp = fmaxf(arg, 0.0f) + __logf(1.0f + __expf(-fabsf(arg)));
        tsum += (s_agei[il] < aj) ? sp : 0.0f;
      }
    }
  }

#pragma unroll
  for (int off = 32; off > 0; off >>= 1) tsum += __shfl_down(tsum, off, 64);
  if (lane == 0) wsum[wv] = tsum;
  __syncthreads();
  if (t == 0)
    atomicAdd(out, (wsum[0] + wsum[1] + wsum[2] + wsum[3]) * INV_NORM);
}

extern "C" void kernel_launch(void* const* d_in, const int* in_sizes, int n_in,
                              void* d_out, int out_size, void* d_ws, size_t ws_size,
                              hipStream_t stream) {
  const float* z = (const float*)d_in[0];
  const int* ages = (const int*)d_in[1];
  const float* proxies = (const float*)d_in[2];
  float* out = (float*)d_out;

  char* ws = (char*)d_ws;
  bf16_t* zb  = (bf16_t*)ws;                                  // 4 MB
  bf16_t* ub  = (bf16_t*)(ws + (size_t)4 * 1024 * 1024);      // 128 KB
  float*  zut = (float*) (ws + (size_t)6 * 1024 * 1024);      // 2 MB (128x4096 f32)
  float*  sq     = (float*)(ws + (size_t)8 * 1024 * 1024);    // 16 KB
  int*    ages_s = (int*)  (ws + (size_t)8 * 1024 * 1024 + 16384);

  prep_kernel<<<528, 512, 0, stream>>>(z, ages, proxies, zb, ub, sq, ages_s, out);
  zu_kernel<<<32, 256, 0, stream>>>(zb, ub, zut);
  pair_kernel<<<NTILES, 256, 0, stream>>>(zb, zut, sq, ages_s, out);
}